// Round 1
// baseline (1343.206 us; speedup 1.0000x reference)
//
#include <hip/hip_runtime.h>

#define TPB 256

__global__ void k_init_deg(float* deg, int n){
    int i = blockIdx.x*blockDim.x + threadIdx.x;
    if(i < n) deg[i] = 1.0f;           // self-loop contributes 1 to every node
}

__global__ void k_deg_accum(const int* __restrict__ dst, float* deg, int E){
    int i = blockIdx.x*blockDim.x + threadIdx.x;
    if(i < E) atomicAdd(&deg[dst[i]], 1.0f);
}

__global__ void k_dinv(float* deg, int n){
    int i = blockIdx.x*blockDim.x + threadIdx.x;
    if(i < n) deg[i] = rsqrtf(deg[i]); // deg >= 1 always (self-loop)
}

// norm[e] = dinv[src]*dinv[dst]; edges [0,E) from edge_index, [E,E+n) self-loops
__global__ void k_norm(const int* __restrict__ ei, const float* __restrict__ dinv,
                       float* __restrict__ norm, int E, int n){
    int e = blockIdx.x*blockDim.x + threadIdx.x;
    if(e < E + n){
        int s = (e < E) ? ei[e]     : (e - E);
        int d = (e < E) ? ei[E + e] : (e - E);
        norm[e] = dinv[s]*dinv[d];
    }
}

// t = h @ W   (h: n x fin, W: fin x fout row-major), W staged in LDS
__global__ void k_gemm(const float* __restrict__ h, const float* __restrict__ W,
                       float* __restrict__ t, int n, int fin, int fout){
    extern __shared__ float sW[];
    for(int i = threadIdx.x; i < fin*fout; i += blockDim.x) sW[i] = W[i];
    __syncthreads();
    unsigned idx = blockIdx.x*blockDim.x + threadIdx.x;
    unsigned total = (unsigned)n * (unsigned)fout;
    if(idx < total){
        unsigned row = idx / fout;
        unsigned col = idx - row*fout;
        const float* hr = h + (size_t)row*fin;
        float s = 0.f;
        #pragma unroll 4
        for(int k = 0; k < fin; k++) s += hr[k]*sW[k*fout + col];
        t[idx] = s;
    }
}

// out[i*f + c] = b[c]  (bias pre-init; scatter adds on top)
__global__ void k_bias_init(float* __restrict__ out, const float* __restrict__ b,
                            unsigned total, int fout){
    unsigned idx = blockIdx.x*blockDim.x + threadIdx.x;
    if(idx < total){
        unsigned col = idx % fout;
        out[idx] = b[col];
    }
}

// for each (edge, col): out[dst, col] += t[src, col] * norm[e]
__global__ void k_scatter(const int* __restrict__ ei, const float* __restrict__ norm,
                          const float* __restrict__ t, float* __restrict__ out,
                          int E, int n, int fout){
    unsigned idx = blockIdx.x*blockDim.x + threadIdx.x;
    unsigned total = (unsigned)(E + n) * (unsigned)fout;
    if(idx < total){
        unsigned e = idx / fout;
        unsigned col = idx - e*fout;
        int s = ((int)e < E) ? ei[e]         : ((int)e - E);
        int d = ((int)e < E) ? ei[E + (int)e] : ((int)e - E);
        float v = t[(unsigned)s*fout + col] * norm[e];
        atomicAdd(&out[(unsigned)d*fout + col], v);
    }
}

__global__ void k_relu(float* __restrict__ x, unsigned total){
    unsigned i = blockIdx.x*blockDim.x + threadIdx.x;
    if(i < total) x[i] = fmaxf(x[i], 0.f);
}

__global__ void k_pool_init(float* p, int total){
    int i = blockIdx.x*blockDim.x + threadIdx.x;
    if(i < total) p[i] = 0.f;   // valid floor: post-ReLU values >= 0, segments non-empty
}

// segment max via uint atomicMax (monotone for non-negative floats)
__global__ void k_pool(const float* __restrict__ h, const int* __restrict__ batch,
                       float* __restrict__ pooled, int n, int f){
    unsigned idx = blockIdx.x*blockDim.x + threadIdx.x;
    unsigned total = (unsigned)n * (unsigned)f;
    if(idx < total){
        unsigned row = idx / f;
        unsigned col = idx - row*f;
        unsigned bits = __float_as_uint(h[idx]);
        atomicMax((unsigned*)&pooled[(unsigned)batch[row]*f + col], bits);
    }
}

// One block per graph g, blockDim = H (128).
// x2 = relu(feature[g] @ Wf1 + bf1) @ Wf2 + bf2 ; x1 = relu(pooled[g]·Wg + bg)
// out[g] = x1 + x2
__global__ void k_head(const float* __restrict__ feature, const float* __restrict__ Wf1,
                       const float* __restrict__ bf1, const float* __restrict__ Wf2,
                       const float* __restrict__ bf2, const float* __restrict__ pooled,
                       const float* __restrict__ Wg, const float* __restrict__ bg,
                       float* __restrict__ out, int FEAT, int H, int F){
    extern __shared__ float smem[];   // FEAT feature row + 4 reduction slots
    int g = blockIdx.x;
    const float* fr = feature + (size_t)g*FEAT;
    for(int i = threadIdx.x; i < FEAT; i += blockDim.x) smem[i] = fr[i];
    __syncthreads();

    int f = threadIdx.x;              // 0..H-1
    float s = bf1[f];
    for(int k = 0; k < FEAT; k++) s += smem[k]*Wf1[k*H + f];   // coalesced Wf1 rows
    float c = fmaxf(s, 0.f) * Wf2[f];

    float x1p = (f < F) ? pooled[(size_t)g*F + f]*Wg[f] : 0.f; // only wave 0 lanes < F
    for(int off = 32; off; off >>= 1){
        c   += __shfl_down(c,   off, 64);
        x1p += __shfl_down(x1p, off, 64);
    }
    float* red = smem + FEAT;
    if((threadIdx.x & 63) == 0){
        red[threadIdx.x >> 6]     = c;
        red[2 + (threadIdx.x >> 6)] = x1p;
    }
    __syncthreads();
    if(threadIdx.x == 0){
        float x2 = red[0] + red[1] + bf2[0];
        float x1 = fmaxf(red[2] + red[3] + bg[0], 0.f);
        out[g] = x1 + x2;
    }
}

static inline int cdiv(long long a, int b){ return (int)((a + b - 1)/b); }

extern "C" void kernel_launch(void* const* d_in, const int* in_sizes, int n_in,
                              void* d_out, int out_size, void* d_ws, size_t ws_size,
                              hipStream_t stream) {
    const float* x       = (const float*)d_in[0];
    const int*   ei      = (const int*)  d_in[1];
    const int*   batch   = (const int*)  d_in[2];
    const float* feature = (const float*)d_in[3];
    const float* W1 = (const float*)d_in[4];  const float* b1 = (const float*)d_in[5];
    const float* W2 = (const float*)d_in[6];  const float* b2 = (const float*)d_in[7];
    const float* W3 = (const float*)d_in[8];  const float* b3 = (const float*)d_in[9];
    const float* Wg = (const float*)d_in[10]; const float* bg = (const float*)d_in[11];
    const float* Wf1= (const float*)d_in[12]; const float* bf1= (const float*)d_in[13];
    const float* Wf2= (const float*)d_in[14]; const float* bf2= (const float*)d_in[15];
    float* out = (float*)d_out;

    const int N    = in_sizes[2];          // 100000
    const int E    = in_sizes[1] / 2;      // 1000000
    const int G    = out_size;             // 1024
    const int F    = in_sizes[5];          // 44
    const int F2   = in_sizes[7];          // 88
    const int FEAT = in_sizes[3] / G;      // 1019
    const int H    = in_sizes[13];         // 128
    const int EN   = E + N;

    // workspace layout (floats)
    float* ws    = (float*)d_ws;
    float* deg   = ws;                         // N   (becomes dinv in place)
    float* norm  = deg  + N;                   // E+N
    float* tbuf  = norm + EN;                  // N*F2
    float* hbuf  = tbuf + (size_t)N*F2;        // N*F2
    float* pooled= hbuf + (size_t)N*F2;        // G*F

    // ---- degrees & norms ----
    k_init_deg <<<cdiv(N,TPB),   TPB, 0, stream>>>(deg, N);
    k_deg_accum<<<cdiv(E,TPB),   TPB, 0, stream>>>(ei + E, deg, E);
    k_dinv     <<<cdiv(N,TPB),   TPB, 0, stream>>>(deg, N);
    k_norm     <<<cdiv(EN,TPB),  TPB, 0, stream>>>(ei, deg, norm, E, N);

    // ---- conv1: x(N,F) @ W1(F,F) -> scatter -> relu -> hbuf(N,F) ----
    {
        unsigned tot = (unsigned)N*F;
        k_gemm<<<cdiv(tot,TPB), TPB, F*F*sizeof(float), stream>>>(x, W1, tbuf, N, F, F);
        k_bias_init<<<cdiv(tot,TPB), TPB, 0, stream>>>(hbuf, b1, tot, F);
        unsigned stot = (unsigned)EN*F;
        k_scatter<<<cdiv(stot,TPB), TPB, 0, stream>>>(ei, norm, tbuf, hbuf, E, N, F);
        k_relu<<<cdiv(tot,TPB), TPB, 0, stream>>>(hbuf, tot);
    }
    // ---- conv2: hbuf(N,F) @ W2(F,F2) -> scatter -> relu -> hbuf(N,F2) ----
    {
        unsigned tot = (unsigned)N*F2;
        k_gemm<<<cdiv(tot,TPB), TPB, F*F2*sizeof(float), stream>>>(hbuf, W2, tbuf, N, F, F2);
        k_bias_init<<<cdiv(tot,TPB), TPB, 0, stream>>>(hbuf, b2, tot, F2);
        unsigned stot = (unsigned)EN*F2;
        k_scatter<<<cdiv(stot,TPB), TPB, 0, stream>>>(ei, norm, tbuf, hbuf, E, N, F2);
        k_relu<<<cdiv(tot,TPB), TPB, 0, stream>>>(hbuf, tot);
    }
    // ---- conv3: hbuf(N,F2) @ W3(F2,F) -> scatter -> relu -> hbuf(N,F) ----
    {
        unsigned tot = (unsigned)N*F;
        k_gemm<<<cdiv(tot,TPB), TPB, F2*F*sizeof(float), stream>>>(hbuf, W3, tbuf, N, F2, F);
        // NOTE: tbuf write happens before hbuf overwrite; stream order guarantees safety
        k_bias_init<<<cdiv(tot,TPB), TPB, 0, stream>>>(hbuf, b3, tot, F);
        unsigned stot = (unsigned)EN*F;
        k_scatter<<<cdiv(stot,TPB), TPB, 0, stream>>>(ei, norm, tbuf, hbuf, E, N, F);
        k_relu<<<cdiv(tot,TPB), TPB, 0, stream>>>(hbuf, tot);
    }
    // ---- global max pool ----
    k_pool_init<<<cdiv((long long)G*F,TPB), TPB, 0, stream>>>(pooled, G*F);
    k_pool<<<cdiv((long long)N*F,TPB), TPB, 0, stream>>>(hbuf, batch, pooled, N, F);

    // ---- heads ----
    k_head<<<G, H, (FEAT + 4)*sizeof(float), stream>>>(
        feature, Wf1, bf1, Wf2, bf2, pooled, Wg, bg, out, FEAT, H, F);
}

// Round 2
// 598.233 us; speedup vs baseline: 2.2453x; 2.2453x over previous
//
#include <hip/hip_runtime.h>

#define TPB 256

static inline int cdiv(long long a, int b){ return (int)((a + b - 1)/b); }

// ---------- CSR build ----------

__global__ void k_deg_init(int* deg, int n){
    int i = blockIdx.x*blockDim.x + threadIdx.x;
    if(i < n) deg[i] = 0;                 // in-edge count (self-loop handled analytically)
}

__global__ void k_deg_count(const int* __restrict__ dst, int* deg, int E){
    int i = blockIdx.x*blockDim.x + threadIdx.x;
    if(i < E) atomicAdd(&deg[dst[i]], 1);
}

__global__ void k_dinv(const int* __restrict__ deg, float* __restrict__ dinv, int n){
    int i = blockIdx.x*blockDim.x + threadIdx.x;
    if(i < n) dinv[i] = rsqrtf((float)(deg[i] + 1));   // +1 = self-loop
}

// per-block inclusive scan of deg -> cursor; block totals -> partial
__global__ void k_scan1(const int* __restrict__ deg, int* __restrict__ cursor,
                        int* __restrict__ partial, int n){
    __shared__ int s[TPB];
    int i = blockIdx.x*TPB + threadIdx.x;
    int t = threadIdx.x;
    s[t] = (i < n) ? deg[i] : 0;
    __syncthreads();
    for(int off = 1; off < TPB; off <<= 1){
        int u = (t >= off) ? s[t-off] : 0;
        __syncthreads();
        s[t] += u;
        __syncthreads();
    }
    if(i < n) cursor[i] = s[t];
    if(t == TPB-1) partial[blockIdx.x] = s[TPB-1];
}

// exclusive scan of partial[m] in one 512-thread block (m <= 512; N=100k -> m=391)
__global__ void k_scan2(int* partial, int m){
    __shared__ int s[512];
    int t = threadIdx.x;
    s[t] = (t < m) ? partial[t] : 0;
    __syncthreads();
    for(int off = 1; off < 512; off <<= 1){
        int u = (t >= off) ? s[t-off] : 0;
        __syncthreads();
        s[t] += u;
        __syncthreads();
    }
    if(t < m) partial[t] = (t == 0) ? 0 : s[t-1];
}

// cursor[i] := global exclusive offset
__global__ void k_scan3(int* __restrict__ cursor, const int* __restrict__ deg,
                        const int* __restrict__ partial, int n){
    int i = blockIdx.x*TPB + threadIdx.x;
    if(i < n) cursor[i] = cursor[i] - deg[i] + partial[blockIdx.x];
}

// fill CSR; afterwards cursor[d] == end offset of node d
__global__ void k_fill(const int* __restrict__ ei, int* cursor,
                       int* __restrict__ csr_src, int E){
    int e = blockIdx.x*blockDim.x + threadIdx.x;
    if(e < E){
        int s_ = ei[e];
        int d_ = ei[E + e];
        int pos = atomicAdd(&cursor[d_], 1);
        csr_src[pos] = s_;
    }
}

// ---------- compute ----------

// t = h @ W, optional row-prescale by dinv, optional bias+relu. fout = 4*fout4.
__global__ void k_gemm(const float* __restrict__ h, const float* __restrict__ W,
                       float* __restrict__ t, int n, int fin, int fout4,
                       const float* __restrict__ dinv, const float* __restrict__ bias){
    extern __shared__ float sW[];
    int fout = fout4*4;
    for(int i = threadIdx.x; i < fin*fout; i += blockDim.x) sW[i] = W[i];
    __syncthreads();
    unsigned idx = blockIdx.x*blockDim.x + threadIdx.x;
    unsigned total = (unsigned)n * (unsigned)fout4;
    if(idx >= total) return;
    unsigned row = idx / fout4;
    unsigned cg  = idx - row*fout4;
    const float* hr = h + (size_t)row*fin;
    const float4* sWv = (const float4*)sW;
    float4 acc = {0.f,0.f,0.f,0.f};
    for(int k = 0; k < fin; k++){
        float hv = hr[k];
        float4 w = sWv[(unsigned)k*fout4 + cg];
        acc.x += hv*w.x; acc.y += hv*w.y; acc.z += hv*w.z; acc.w += hv*w.w;
    }
    if(bias){
        const float4* bv = (const float4*)bias;
        float4 b = bv[cg];
        acc.x = fmaxf(acc.x + b.x, 0.f); acc.y = fmaxf(acc.y + b.y, 0.f);
        acc.z = fmaxf(acc.z + b.z, 0.f); acc.w = fmaxf(acc.w + b.w, 0.f);
    }
    if(dinv){
        float dd = dinv[row];
        acc.x *= dd; acc.y *= dd; acc.z *= dd; acc.w *= dd;
    }
    ((float4*)t)[idx] = acc;
}

// out[d] = f( dinv[d] * (t[d] + sum_{s->d} t[s]) )   (t rows pre-scaled by dinv upstream)
// bias!=0 : relu(v + bias);  prescale_out : multiply result by dinv[d] again
__global__ void k_gather(const int* __restrict__ cursor, const int* __restrict__ csr_src,
                         const float* __restrict__ t, const float* __restrict__ dinv,
                         const float* __restrict__ bias, float* __restrict__ out,
                         int n, int f4, int prescale_out){
    unsigned idx = blockIdx.x*blockDim.x + threadIdx.x;
    unsigned total = (unsigned)n * (unsigned)f4;
    if(idx >= total) return;
    unsigned d  = idx / f4;
    unsigned cg = idx - d*f4;
    int start = (d == 0) ? 0 : cursor[d-1];
    int end   = cursor[d];
    const float4* tv = (const float4*)t;
    float4 acc = tv[(size_t)d*f4 + cg];          // self-loop contribution
    int j = start;
    if(j < end){
        int sCur = csr_src[j];
        while(true){
            j++;
            int sNext = (j < end) ? csr_src[j] : 0;   // prefetch next index
            float4 v = tv[(size_t)sCur*f4 + cg];
            acc.x += v.x; acc.y += v.y; acc.z += v.z; acc.w += v.w;
            if(j >= end) break;
            sCur = sNext;
        }
    }
    float dd = dinv[d];
    acc.x *= dd; acc.y *= dd; acc.z *= dd; acc.w *= dd;
    if(bias){
        const float4* bv = (const float4*)bias;
        float4 b = bv[cg];
        acc.x = fmaxf(acc.x + b.x, 0.f); acc.y = fmaxf(acc.y + b.y, 0.f);
        acc.z = fmaxf(acc.z + b.z, 0.f); acc.w = fmaxf(acc.w + b.w, 0.f);
    }
    if(prescale_out){
        acc.x *= dd; acc.y *= dd; acc.z *= dd; acc.w *= dd;
    }
    ((float4*)out)[idx] = acc;
}

__global__ void k_pool_init(float* p, int total){
    int i = blockIdx.x*blockDim.x + threadIdx.x;
    if(i < total) p[i] = 0.f;   // valid floor: post-ReLU values >= 0, all segments non-empty
}

// segment max via uint atomicMax (monotone for non-negative floats); 4 cols/thread
__global__ void k_pool(const float* __restrict__ h, const int* __restrict__ batch,
                       float* __restrict__ pooled, int n, int f4){
    unsigned idx = blockIdx.x*blockDim.x + threadIdx.x;
    unsigned total = (unsigned)n * (unsigned)f4;
    if(idx >= total) return;
    unsigned row = idx / f4;
    unsigned cg  = idx - row*f4;
    float4 v = ((const float4*)h)[idx];
    unsigned* pb = (unsigned*)(pooled + (size_t)batch[row]*f4*4 + cg*4);
    atomicMax(pb+0, __float_as_uint(v.x));
    atomicMax(pb+1, __float_as_uint(v.y));
    atomicMax(pb+2, __float_as_uint(v.z));
    atomicMax(pb+3, __float_as_uint(v.w));
}

// One block per graph g, blockDim = H (128).
__global__ void k_head(const float* __restrict__ feature, const float* __restrict__ Wf1,
                       const float* __restrict__ bf1, const float* __restrict__ Wf2,
                       const float* __restrict__ bf2, const float* __restrict__ pooled,
                       const float* __restrict__ Wg, const float* __restrict__ bg,
                       float* __restrict__ out, int FEAT, int H, int F){
    extern __shared__ float smem[];   // FEAT feature row + 4 reduction slots
    int g = blockIdx.x;
    const float* fr = feature + (size_t)g*FEAT;
    for(int i = threadIdx.x; i < FEAT; i += blockDim.x) smem[i] = fr[i];
    __syncthreads();

    int f = threadIdx.x;
    float s = bf1[f];
    for(int k = 0; k < FEAT; k++) s += smem[k]*Wf1[k*H + f];
    float c = fmaxf(s, 0.f) * Wf2[f];

    float x1p = (f < F) ? pooled[(size_t)g*F + f]*Wg[f] : 0.f;
    for(int off = 32; off; off >>= 1){
        c   += __shfl_down(c,   off, 64);
        x1p += __shfl_down(x1p, off, 64);
    }
    float* red = smem + FEAT;
    if((threadIdx.x & 63) == 0){
        red[threadIdx.x >> 6]       = c;
        red[2 + (threadIdx.x >> 6)] = x1p;
    }
    __syncthreads();
    if(threadIdx.x == 0){
        float x2 = red[0] + red[1] + bf2[0];
        float x1 = fmaxf(red[2] + red[3] + bg[0], 0.f);
        out[g] = x1 + x2;
    }
}

extern "C" void kernel_launch(void* const* d_in, const int* in_sizes, int n_in,
                              void* d_out, int out_size, void* d_ws, size_t ws_size,
                              hipStream_t stream) {
    const float* x       = (const float*)d_in[0];
    const int*   ei      = (const int*)  d_in[1];
    const int*   batch   = (const int*)  d_in[2];
    const float* feature = (const float*)d_in[3];
    const float* W1 = (const float*)d_in[4];  const float* b1 = (const float*)d_in[5];
    const float* W2 = (const float*)d_in[6];  const float* b2 = (const float*)d_in[7];
    const float* W3 = (const float*)d_in[8];  const float* b3 = (const float*)d_in[9];
    const float* Wg = (const float*)d_in[10]; const float* bg = (const float*)d_in[11];
    const float* Wf1= (const float*)d_in[12]; const float* bf1= (const float*)d_in[13];
    const float* Wf2= (const float*)d_in[14]; const float* bf2= (const float*)d_in[15];
    float* out = (float*)d_out;

    const int N    = in_sizes[2];          // 100000
    const int E    = in_sizes[1] / 2;      // 1000000
    const int G    = out_size;             // 1024
    const int F    = in_sizes[5];          // 44
    const int F2   = in_sizes[7];          // 88
    const int FEAT = in_sizes[3] / G;      // 1019
    const int H    = in_sizes[13];         // 128
    const int F4   = F  / 4;               // 11
    const int F24  = F2 / 4;               // 22

    // workspace layout (4B units) — total == 18,845,056 floats (same as round-1)
    float* wsf    = (float*)d_ws;
    float* dinv   = wsf;                        // N floats
    int*   cursor = (int*)(dinv + N);           // N ints
    int*   csr    = cursor + N;                 // E ints
    float* bufA   = (float*)(csr + E);          // N*F
    float* bufB   = bufA + (size_t)N*F;         // N*F2
    float* bufC   = bufB + (size_t)N*F2;        // N*F
    float* pooled = bufC + (size_t)N*F;         // G*F
    // deg + partial time-share bufB (dead before bufB's first write in conv2 GEMM)
    int*   deg     = (int*)bufB;                // N ints
    int*   partial = deg + N;                   // <=512 ints

    const int nScanBlocks = cdiv(N, TPB);       // 391 (<=512 required by k_scan2)

    // ---- CSR build ----
    k_deg_init <<<cdiv(N,TPB), TPB, 0, stream>>>(deg, N);
    k_deg_count<<<cdiv(E,TPB), TPB, 0, stream>>>(ei + E, deg, E);
    k_dinv     <<<cdiv(N,TPB), TPB, 0, stream>>>(deg, dinv, N);
    k_scan1    <<<nScanBlocks, TPB, 0, stream>>>(deg, cursor, partial, N);
    k_scan2    <<<1, 512, 0, stream>>>(partial, nScanBlocks);
    k_scan3    <<<nScanBlocks, TPB, 0, stream>>>(cursor, deg, partial, N);
    k_fill     <<<cdiv(E,TPB), TPB, 0, stream>>>(ei, cursor, csr, E);

    // ---- conv1 (transform-first): t' = dinv.*(x@W1) ; h1' = dinv.*relu(dinv*agg + b1) ----
    {
        unsigned tot = (unsigned)N*F4;
        k_gemm<<<cdiv(tot,TPB), TPB, F*F*sizeof(float), stream>>>(x, W1, bufA, N, F, F4, dinv, nullptr);
        k_gather<<<cdiv(tot,TPB), TPB, 0, stream>>>(cursor, csr, bufA, dinv, b1, bufC, N, F4, 1);
    }
    // ---- conv2 (aggregate-first): a = dinv*agg(h1') ; h2 = relu(a@W2 + b2) ----
    {
        unsigned tot = (unsigned)N*F4;
        k_gather<<<cdiv(tot,TPB), TPB, 0, stream>>>(cursor, csr, bufC, dinv, nullptr, bufA, N, F4, 0);
        unsigned tot2 = (unsigned)N*F24;
        k_gemm<<<cdiv(tot2,TPB), TPB, F*F2*sizeof(float), stream>>>(bufA, W2, bufB, N, F, F24, nullptr, b2);
    }
    // ---- conv3 (transform-first): t' = dinv.*(h2@W3) ; h3 = relu(dinv*agg + b3) ----
    {
        unsigned tot = (unsigned)N*F4;
        k_gemm<<<cdiv(tot,TPB), TPB, F2*F*sizeof(float), stream>>>(bufB, W3, bufA, N, F2, F4, dinv, nullptr);
        k_gather<<<cdiv(tot,TPB), TPB, 0, stream>>>(cursor, csr, bufA, dinv, b3, bufC, N, F4, 0);
    }
    // ---- global max pool ----
    k_pool_init<<<cdiv((long long)G*F,TPB), TPB, 0, stream>>>(pooled, G*F);
    k_pool<<<cdiv((long long)N*F4,TPB), TPB, 0, stream>>>(bufC, batch, pooled, N, F4);

    // ---- heads ----
    k_head<<<G, H, (FEAT + 4)*sizeof(float), stream>>>(
        feature, Wf1, bf1, Wf2, bf2, pooled, Wg, bg, out, FEAT, H, F);
}

// Round 3
// 497.316 us; speedup vs baseline: 2.7009x; 1.2029x over previous
//
#include <hip/hip_runtime.h>

#define TPB 256

static inline int cdiv(long long a, int b){ return (int)((a + b - 1)/b); }

// ---------- CSR build ----------

__global__ void k_deg_init(int* deg, int n){
    int i = blockIdx.x*blockDim.x + threadIdx.x;
    if(i < n) deg[i] = 0;                 // in-edge count (self-loop handled analytically)
}

__global__ void k_deg_count(const int* __restrict__ dst, int* deg, int E){
    int i = blockIdx.x*blockDim.x + threadIdx.x;
    if(i < E) atomicAdd(&deg[dst[i]], 1);
}

__global__ void k_dinv(const int* __restrict__ deg, float* __restrict__ dinv, int n){
    int i = blockIdx.x*blockDim.x + threadIdx.x;
    if(i < n) dinv[i] = rsqrtf((float)(deg[i] + 1));   // +1 = self-loop
}

// per-block inclusive scan of deg -> cursor; block totals -> partial
__global__ void k_scan1(const int* __restrict__ deg, int* __restrict__ cursor,
                        int* __restrict__ partial, int n){
    __shared__ int s[TPB];
    int i = blockIdx.x*TPB + threadIdx.x;
    int t = threadIdx.x;
    s[t] = (i < n) ? deg[i] : 0;
    __syncthreads();
    for(int off = 1; off < TPB; off <<= 1){
        int u = (t >= off) ? s[t-off] : 0;
        __syncthreads();
        s[t] += u;
        __syncthreads();
    }
    if(i < n) cursor[i] = s[t];
    if(t == TPB-1) partial[blockIdx.x] = s[TPB-1];
}

// exclusive scan of partial[m] in one 512-thread block (m <= 512; N=100k -> m=391)
__global__ void k_scan2(int* partial, int m){
    __shared__ int s[512];
    int t = threadIdx.x;
    s[t] = (t < m) ? partial[t] : 0;
    __syncthreads();
    for(int off = 1; off < 512; off <<= 1){
        int u = (t >= off) ? s[t-off] : 0;
        __syncthreads();
        s[t] += u;
        __syncthreads();
    }
    if(t < m) partial[t] = (t == 0) ? 0 : s[t-1];
}

// cursor[i] := global exclusive offset
__global__ void k_scan3(int* __restrict__ cursor, const int* __restrict__ deg,
                        const int* __restrict__ partial, int n){
    int i = blockIdx.x*TPB + threadIdx.x;
    if(i < n) cursor[i] = cursor[i] - deg[i] + partial[blockIdx.x];
}

// fill CSR; afterwards cursor[d] == end offset of node d
__global__ void k_fill(const int* __restrict__ ei, int* cursor,
                       int* __restrict__ csr_src, int E){
    int e = blockIdx.x*blockDim.x + threadIdx.x;
    if(e < E){
        int s_ = ei[e];
        int d_ = ei[E + e];
        int pos = atomicAdd(&cursor[d_], 1);
        csr_src[pos] = s_;
    }
}

// ---------- compute ----------

// t = h @ W, optional row-prescale by dinv, optional bias+relu. fout = 4*fout4.
__global__ void k_gemm(const float* __restrict__ h, const float* __restrict__ W,
                       float* __restrict__ t, int n, int fin, int fout4,
                       const float* __restrict__ dinv, const float* __restrict__ bias){
    extern __shared__ float sW[];
    int fout = fout4*4;
    for(int i = threadIdx.x; i < fin*fout; i += blockDim.x) sW[i] = W[i];
    __syncthreads();
    unsigned idx = blockIdx.x*blockDim.x + threadIdx.x;
    unsigned total = (unsigned)n * (unsigned)fout4;
    if(idx >= total) return;
    unsigned row = idx / fout4;
    unsigned cg  = idx - row*fout4;
    const float* hr = h + (size_t)row*fin;
    const float4* sWv = (const float4*)sW;
    float4 acc = {0.f,0.f,0.f,0.f};
    for(int k = 0; k < fin; k++){
        float hv = hr[k];
        float4 w = sWv[(unsigned)k*fout4 + cg];
        acc.x += hv*w.x; acc.y += hv*w.y; acc.z += hv*w.z; acc.w += hv*w.w;
    }
    if(bias){
        const float4* bv = (const float4*)bias;
        float4 b = bv[cg];
        acc.x = fmaxf(acc.x + b.x, 0.f); acc.y = fmaxf(acc.y + b.y, 0.f);
        acc.z = fmaxf(acc.z + b.z, 0.f); acc.w = fmaxf(acc.w + b.w, 0.f);
    }
    if(dinv){
        float dd = dinv[row];
        acc.x *= dd; acc.y *= dd; acc.z *= dd; acc.w *= dd;
    }
    ((float4*)t)[idx] = acc;
}

// out[d] = f( dinv[d] * (t[d] + sum_{s->d} t[s]) )   (t rows pre-scaled by dinv upstream)
// bias!=0 : relu(v + bias);  prescale_out : multiply result by dinv[d] again
__global__ void k_gather(const int* __restrict__ cursor, const int* __restrict__ csr_src,
                         const float* __restrict__ t, const float* __restrict__ dinv,
                         const float* __restrict__ bias, float* __restrict__ out,
                         int n, int f4, int prescale_out){
    unsigned idx = blockIdx.x*blockDim.x + threadIdx.x;
    unsigned total = (unsigned)n * (unsigned)f4;
    if(idx >= total) return;
    unsigned d  = idx / f4;
    unsigned cg = idx - d*f4;
    int start = (d == 0) ? 0 : cursor[d-1];
    int end   = cursor[d];
    const float4* tv = (const float4*)t;
    float4 acc = tv[(size_t)d*f4 + cg];          // self-loop contribution
    int j = start;
    if(j < end){
        int sCur = csr_src[j];
        while(true){
            j++;
            int sNext = (j < end) ? csr_src[j] : 0;   // prefetch next index
            float4 v = tv[(size_t)sCur*f4 + cg];
            acc.x += v.x; acc.y += v.y; acc.z += v.z; acc.w += v.w;
            if(j >= end) break;
            sCur = sNext;
        }
    }
    float dd = dinv[d];
    acc.x *= dd; acc.y *= dd; acc.z *= dd; acc.w *= dd;
    if(bias){
        const float4* bv = (const float4*)bias;
        float4 b = bv[cg];
        acc.x = fmaxf(acc.x + b.x, 0.f); acc.y = fmaxf(acc.y + b.y, 0.f);
        acc.z = fmaxf(acc.z + b.z, 0.f); acc.w = fmaxf(acc.w + b.w, 0.f);
    }
    if(prescale_out){
        acc.x *= dd; acc.y *= dd; acc.z *= dd; acc.w *= dd;
    }
    ((float4*)out)[idx] = acc;
}

// one block (64 threads) per graph; batch is sorted, segments non-empty.
// 4 row-groups x 16 lanes (lanes 0..f4-1 active); shuffle-combine at the end.
__global__ void k_pool_seg(const float* __restrict__ h, const int* __restrict__ batch,
                           float* __restrict__ pooled, int n, int f4){
    int g = blockIdx.x;
    // lower_bound(batch, g) and lower_bound(batch, g+1), all threads redundantly
    int lo = 0, hi = n;
    while(lo < hi){ int mid = (lo + hi) >> 1; if(batch[mid] < g) lo = mid + 1; else hi = mid; }
    int start = lo;
    hi = n;
    while(lo < hi){ int mid = (lo + hi) >> 1; if(batch[mid] < g + 1) lo = mid + 1; else hi = mid; }
    int end = lo;

    int t   = threadIdx.x;        // 0..63
    int rg  = t >> 4;             // row group 0..3
    int cg  = t & 15;             // column group; active when < f4
    float4 m = {0.f, 0.f, 0.f, 0.f};   // valid floor: inputs are post-ReLU
    if(cg < f4){
        for(int r = start + rg; r < end; r += 4){
            float4 v = ((const float4*)h)[(size_t)r*f4 + cg];
            m.x = fmaxf(m.x, v.x); m.y = fmaxf(m.y, v.y);
            m.z = fmaxf(m.z, v.z); m.w = fmaxf(m.w, v.w);
        }
    }
    // combine the 4 row-groups (lanes differing by 32, then 16)
    for(int off = 32; off >= 16; off >>= 1){
        m.x = fmaxf(m.x, __shfl_xor(m.x, off, 64));
        m.y = fmaxf(m.y, __shfl_xor(m.y, off, 64));
        m.z = fmaxf(m.z, __shfl_xor(m.z, off, 64));
        m.w = fmaxf(m.w, __shfl_xor(m.w, off, 64));
    }
    if(t < f4) ((float4*)pooled)[(size_t)g*f4 + t] = m;
}

// One block per graph g, blockDim = H (128).
__global__ void k_head(const float* __restrict__ feature, const float* __restrict__ Wf1,
                       const float* __restrict__ bf1, const float* __restrict__ Wf2,
                       const float* __restrict__ bf2, const float* __restrict__ pooled,
                       const float* __restrict__ Wg, const float* __restrict__ bg,
                       float* __restrict__ out, int FEAT, int H, int F){
    extern __shared__ float smem[];   // FEAT feature row + 4 reduction slots
    int g = blockIdx.x;
    const float* fr = feature + (size_t)g*FEAT;
    for(int i = threadIdx.x; i < FEAT; i += blockDim.x) smem[i] = fr[i];
    __syncthreads();

    int f = threadIdx.x;
    float s = bf1[f];
    for(int k = 0; k < FEAT; k++) s += smem[k]*Wf1[k*H + f];
    float c = fmaxf(s, 0.f) * Wf2[f];

    float x1p = (f < F) ? pooled[(size_t)g*F + f]*Wg[f] : 0.f;
    for(int off = 32; off; off >>= 1){
        c   += __shfl_down(c,   off, 64);
        x1p += __shfl_down(x1p, off, 64);
    }
    float* red = smem + FEAT;
    if((threadIdx.x & 63) == 0){
        red[threadIdx.x >> 6]       = c;
        red[2 + (threadIdx.x >> 6)] = x1p;
    }
    __syncthreads();
    if(threadIdx.x == 0){
        float x2 = red[0] + red[1] + bf2[0];
        float x1 = fmaxf(red[2] + red[3] + bg[0], 0.f);
        out[g] = x1 + x2;
    }
}

extern "C" void kernel_launch(void* const* d_in, const int* in_sizes, int n_in,
                              void* d_out, int out_size, void* d_ws, size_t ws_size,
                              hipStream_t stream) {
    const float* x       = (const float*)d_in[0];
    const int*   ei      = (const int*)  d_in[1];
    const int*   batch   = (const int*)  d_in[2];
    const float* feature = (const float*)d_in[3];
    const float* W1 = (const float*)d_in[4];  const float* b1 = (const float*)d_in[5];
    const float* W2 = (const float*)d_in[6];  const float* b2 = (const float*)d_in[7];
    const float* W3 = (const float*)d_in[8];  const float* b3 = (const float*)d_in[9];
    const float* Wg = (const float*)d_in[10]; const float* bg = (const float*)d_in[11];
    const float* Wf1= (const float*)d_in[12]; const float* bf1= (const float*)d_in[13];
    const float* Wf2= (const float*)d_in[14]; const float* bf2= (const float*)d_in[15];
    float* out = (float*)d_out;

    const int N    = in_sizes[2];          // 100000
    const int E    = in_sizes[1] / 2;      // 1000000
    const int G    = out_size;             // 1024
    const int F    = in_sizes[5];          // 44
    const int F2   = in_sizes[7];          // 88
    const int FEAT = in_sizes[3] / G;      // 1019
    const int H    = in_sizes[13];         // 128
    const int F4   = F  / 4;               // 11
    const int F24  = F2 / 4;               // 22

    // workspace layout (4B units)
    float* wsf    = (float*)d_ws;
    float* dinv   = wsf;                        // N floats
    int*   cursor = (int*)(dinv + N);           // N ints
    int*   csr    = cursor + N;                 // E ints
    float* bufA   = (float*)(csr + E);          // N*F
    float* bufB   = bufA + (size_t)N*F;         // N*F2
    float* bufC   = bufB + (size_t)N*F2;        // N*F
    float* pooled = bufC + (size_t)N*F;         // G*F
    // deg + partial time-share bufB (dead before bufB's first write in conv2 GEMM)
    int*   deg     = (int*)bufB;                // N ints
    int*   partial = deg + N;                   // <=512 ints

    const int nScanBlocks = cdiv(N, TPB);       // 391 (<=512 required by k_scan2)

    // ---- CSR build ----
    k_deg_init <<<cdiv(N,TPB), TPB, 0, stream>>>(deg, N);
    k_deg_count<<<cdiv(E,TPB), TPB, 0, stream>>>(ei + E, deg, E);
    k_dinv     <<<cdiv(N,TPB), TPB, 0, stream>>>(deg, dinv, N);
    k_scan1    <<<nScanBlocks, TPB, 0, stream>>>(deg, cursor, partial, N);
    k_scan2    <<<1, 512, 0, stream>>>(partial, nScanBlocks);
    k_scan3    <<<nScanBlocks, TPB, 0, stream>>>(cursor, deg, partial, N);
    k_fill     <<<cdiv(E,TPB), TPB, 0, stream>>>(ei, cursor, csr, E);

    // ---- conv1 (transform-first): t' = dinv.*(x@W1) ; h1' = dinv.*relu(dinv*agg + b1) ----
    {
        unsigned tot = (unsigned)N*F4;
        k_gemm<<<cdiv(tot,TPB), TPB, F*F*sizeof(float), stream>>>(x, W1, bufA, N, F, F4, dinv, nullptr);
        k_gather<<<cdiv(tot,TPB), TPB, 0, stream>>>(cursor, csr, bufA, dinv, b1, bufC, N, F4, 1);
    }
    // ---- conv2 (aggregate-first): a = dinv*agg(h1') ; h2 = relu(a@W2 + b2) ----
    {
        unsigned tot = (unsigned)N*F4;
        k_gather<<<cdiv(tot,TPB), TPB, 0, stream>>>(cursor, csr, bufC, dinv, nullptr, bufA, N, F4, 0);
        unsigned tot2 = (unsigned)N*F24;
        k_gemm<<<cdiv(tot2,TPB), TPB, F*F2*sizeof(float), stream>>>(bufA, W2, bufB, N, F, F24, nullptr, b2);
    }
    // ---- conv3 (transform-first): t' = dinv.*(h2@W3) ; h3 = relu(dinv*agg + b3) ----
    {
        unsigned tot = (unsigned)N*F4;
        k_gemm<<<cdiv(tot,TPB), TPB, F2*F*sizeof(float), stream>>>(bufB, W3, bufA, N, F2, F4, dinv, nullptr);
        k_gather<<<cdiv(tot,TPB), TPB, 0, stream>>>(cursor, csr, bufA, dinv, b3, bufC, N, F4, 0);
    }
    // ---- global max pool (sorted batch -> per-graph block, no atomics) ----
    k_pool_seg<<<G, 64, 0, stream>>>(bufC, batch, pooled, N, F4);

    // ---- heads ----
    k_head<<<G, H, (FEAT + 4)*sizeof(float), stream>>>(
        feature, Wf1, bf1, Wf2, bf2, pooled, Wg, bg, out, FEAT, H, F);
}

// Round 4
// 449.497 us; speedup vs baseline: 2.9882x; 1.1064x over previous
//
#include <hip/hip_runtime.h>

#define TPB 256
#define NBLK1 256          // pass-1 blocks
#define BSH 10             // bucket shift: 1024 nodes per bucket
#define MAXBE 12288        // max edges/bucket (mean 10240, +20 sigma) -> 48KB LDS

static inline int cdiv(long long a, int b){ return (int)((a + b - 1)/b); }

// ---------- CSR build: two-level counting sort, no global atomics ----------

// per-block LDS histogram over coarse buckets -> cnt_t[b*NBLK1 + blk]
__global__ void k_bcount(const int* __restrict__ dst, int* __restrict__ cnt_t,
                         int E, int NB, int chunk){
    __shared__ int hist[256];
    int blk = blockIdx.x;
    for(int i = threadIdx.x; i < NB; i += blockDim.x) hist[i] = 0;
    __syncthreads();
    int lo = blk*chunk, hi = min(E, lo + chunk);
    for(int e = lo + threadIdx.x; e < hi; e += blockDim.x)
        atomicAdd(&hist[dst[e] >> BSH], 1);
    __syncthreads();
    for(int b = threadIdx.x; b < NB; b += blockDim.x)
        cnt_t[b*NBLK1 + blk] = hist[b];
}

// in-place exclusive scan of cnt_t[M], single block of 1024 threads
__global__ void k_bscan(int* __restrict__ cnt_t, int M){
    __shared__ int part[1024];
    int t = threadIdx.x;
    int IT = (M + 1023) >> 10;
    int base = t*IT;
    int s = 0;
    for(int i = 0; i < IT; i++){ int k = base + i; if(k < M) s += cnt_t[k]; }
    part[t] = s;
    __syncthreads();
    for(int off = 1; off < 1024; off <<= 1){
        int u = (t >= off) ? part[t-off] : 0;
        __syncthreads();
        part[t] += u;
        __syncthreads();
    }
    int run = (t == 0) ? 0 : part[t-1];
    for(int i = 0; i < IT; i++){
        int k = base + i;
        if(k < M){ int v = cnt_t[k]; cnt_t[k] = run; run += v; }
    }
}

// scatter (src,dst) pairs into block-private contiguous sub-regions per bucket
__global__ void k_bscatter(const int* __restrict__ ei, const int* __restrict__ cnt_t,
                           int2* __restrict__ pairs, int E, int NB, int chunk){
    __shared__ int cur[256];
    int blk = blockIdx.x;
    for(int b = threadIdx.x; b < NB; b += blockDim.x) cur[b] = cnt_t[b*NBLK1 + blk];
    __syncthreads();
    int lo = blk*chunk, hi = min(E, lo + chunk);
    for(int e = lo + threadIdx.x; e < hi; e += blockDim.x){
        int s = ei[e], d = ei[E + e];
        int pos = atomicAdd(&cur[d >> BSH], 1);    // LDS atomic
        pairs[pos] = make_int2(s, d);
    }
}

// one block per bucket: local count+scan -> deg/dinv/cursor + LDS-built CSR segment
__global__ void k_build(const int2* __restrict__ pairs, const int* __restrict__ cnt_t,
                        int* __restrict__ csr, int* __restrict__ cursor,
                        float* __restrict__ dinv, int N, int E, int NB){
    __shared__ int c[1024];
    __shared__ int so[1024];
    __shared__ int part[256];
    __shared__ int csrl[MAXBE];
    int b    = blockIdx.x;
    int n0   = b << BSH;
    int nn   = min(1024, N - n0);
    int base = cnt_t[b*NBLK1];
    int end  = (b+1 < NB) ? cnt_t[(b+1)*NBLK1] : E;
    int cntE = end - base;
    int t = threadIdx.x;
    for(int i = t; i < 1024; i += 256) c[i] = 0;
    __syncthreads();
    for(int i = t; i < cntE; i += 256)
        atomicAdd(&c[pairs[base + i].y - n0], 1);   // LDS atomic
    __syncthreads();
    // exclusive scan of c[1024], 4 elements per thread
    int i0 = t*4;
    int l0 = c[i0], l1 = c[i0+1], l2 = c[i0+2], l3 = c[i0+3];
    part[t] = l0 + l1 + l2 + l3;
    __syncthreads();
    for(int off = 1; off < 256; off <<= 1){
        int u = (t >= off) ? part[t-off] : 0;
        __syncthreads();
        part[t] += u;
        __syncthreads();
    }
    int run = (t == 0) ? 0 : part[t-1];
    so[i0] = run; so[i0+1] = run + l0; so[i0+2] = run + l0 + l1; so[i0+3] = run + l0 + l1 + l2;
    __syncthreads();
    // per-node outputs (contiguous stores)
    for(int i = t; i < nn; i += 256){
        int cc = c[i];
        cursor[n0 + i] = base + so[i] + cc;        // inclusive end offset
        dinv[n0 + i]   = rsqrtf((float)(cc + 1));  // +1 = self-loop
    }
    // reuse c as fill cursor (same t<->i mapping as the reads above: no race)
    for(int i = t; i < 1024; i += 256) c[i] = so[i];
    __syncthreads();
    for(int i = t; i < cntE; i += 256){
        int2 p = pairs[base + i];
        int pos = atomicAdd(&c[p.y - n0], 1);      // LDS atomic
        csrl[pos] = p.x;
    }
    __syncthreads();
    for(int i = t; i < cntE; i += 256) csr[base + i] = csrl[i];   // coalesced
}

// ---------- compute ----------

// t = h @ W, optional row-prescale by dinv, optional bias+relu. fout = 4*fout4.
__global__ void k_gemm(const float* __restrict__ h, const float* __restrict__ W,
                       float* __restrict__ t, int n, int fin, int fout4,
                       const float* __restrict__ dinv, const float* __restrict__ bias){
    extern __shared__ float sW[];
    int fout = fout4*4;
    for(int i = threadIdx.x; i < fin*fout; i += blockDim.x) sW[i] = W[i];
    __syncthreads();
    unsigned idx = blockIdx.x*blockDim.x + threadIdx.x;
    unsigned total = (unsigned)n * (unsigned)fout4;
    if(idx >= total) return;
    unsigned row = idx / fout4;
    unsigned cg  = idx - row*fout4;
    const float* hr = h + (size_t)row*fin;
    const float4* sWv = (const float4*)sW;
    float4 acc = {0.f,0.f,0.f,0.f};
    for(int k = 0; k < fin; k++){
        float hv = hr[k];
        float4 w = sWv[(unsigned)k*fout4 + cg];
        acc.x += hv*w.x; acc.y += hv*w.y; acc.z += hv*w.z; acc.w += hv*w.w;
    }
    if(bias){
        const float4* bv = (const float4*)bias;
        float4 b = bv[cg];
        acc.x = fmaxf(acc.x + b.x, 0.f); acc.y = fmaxf(acc.y + b.y, 0.f);
        acc.z = fmaxf(acc.z + b.z, 0.f); acc.w = fmaxf(acc.w + b.w, 0.f);
    }
    if(dinv){
        float dd = dinv[row];
        acc.x *= dd; acc.y *= dd; acc.z *= dd; acc.w *= dd;
    }
    ((float4*)t)[idx] = acc;
}

// out[d] = f( dinv[d] * (t[d] + sum_{s->d} t[s]) )
__global__ void k_gather(const int* __restrict__ cursor, const int* __restrict__ csr_src,
                         const float* __restrict__ t, const float* __restrict__ dinv,
                         const float* __restrict__ bias, float* __restrict__ out,
                         int n, int f4, int prescale_out){
    unsigned idx = blockIdx.x*blockDim.x + threadIdx.x;
    unsigned total = (unsigned)n * (unsigned)f4;
    if(idx >= total) return;
    unsigned d  = idx / f4;
    unsigned cg = idx - d*f4;
    int start = (d == 0) ? 0 : cursor[d-1];
    int end   = cursor[d];
    const float4* tv = (const float4*)t;
    float4 acc = tv[(size_t)d*f4 + cg];          // self-loop contribution
    int j = start;
    if(j < end){
        int sCur = csr_src[j];
        while(true){
            j++;
            int sNext = (j < end) ? csr_src[j] : 0;
            float4 v = tv[(size_t)sCur*f4 + cg];
            acc.x += v.x; acc.y += v.y; acc.z += v.z; acc.w += v.w;
            if(j >= end) break;
            sCur = sNext;
        }
    }
    float dd = dinv[d];
    acc.x *= dd; acc.y *= dd; acc.z *= dd; acc.w *= dd;
    if(bias){
        const float4* bv = (const float4*)bias;
        float4 b = bv[cg];
        acc.x = fmaxf(acc.x + b.x, 0.f); acc.y = fmaxf(acc.y + b.y, 0.f);
        acc.z = fmaxf(acc.z + b.z, 0.f); acc.w = fmaxf(acc.w + b.w, 0.f);
    }
    if(prescale_out){
        acc.x *= dd; acc.y *= dd; acc.z *= dd; acc.w *= dd;
    }
    ((float4*)out)[idx] = acc;
}

// one block (64 threads) per graph; batch sorted, segments non-empty.
__global__ void k_pool_seg(const float* __restrict__ h, const int* __restrict__ batch,
                           float* __restrict__ pooled, int n, int f4){
    int g = blockIdx.x;
    int lo = 0, hi = n;
    while(lo < hi){ int mid = (lo + hi) >> 1; if(batch[mid] < g) lo = mid + 1; else hi = mid; }
    int start = lo;
    hi = n;
    while(lo < hi){ int mid = (lo + hi) >> 1; if(batch[mid] < g + 1) lo = mid + 1; else hi = mid; }
    int end = lo;

    int t  = threadIdx.x;
    int rg = t >> 4;
    int cg = t & 15;
    float4 m = {0.f, 0.f, 0.f, 0.f};
    if(cg < f4){
        for(int r = start + rg; r < end; r += 4){
            float4 v = ((const float4*)h)[(size_t)r*f4 + cg];
            m.x = fmaxf(m.x, v.x); m.y = fmaxf(m.y, v.y);
            m.z = fmaxf(m.z, v.z); m.w = fmaxf(m.w, v.w);
        }
    }
    for(int off = 32; off >= 16; off >>= 1){
        m.x = fmaxf(m.x, __shfl_xor(m.x, off, 64));
        m.y = fmaxf(m.y, __shfl_xor(m.y, off, 64));
        m.z = fmaxf(m.z, __shfl_xor(m.z, off, 64));
        m.w = fmaxf(m.w, __shfl_xor(m.w, off, 64));
    }
    if(t < f4) ((float4*)pooled)[(size_t)g*f4 + t] = m;
}

// One block per graph g, blockDim = H (128).
__global__ void k_head(const float* __restrict__ feature, const float* __restrict__ Wf1,
                       const float* __restrict__ bf1, const float* __restrict__ Wf2,
                       const float* __restrict__ bf2, const float* __restrict__ pooled,
                       const float* __restrict__ Wg, const float* __restrict__ bg,
                       float* __restrict__ out, int FEAT, int H, int F){
    extern __shared__ float smem[];
    int g = blockIdx.x;
    const float* fr = feature + (size_t)g*FEAT;
    for(int i = threadIdx.x; i < FEAT; i += blockDim.x) smem[i] = fr[i];
    __syncthreads();

    int f = threadIdx.x;
    float s = bf1[f];
    for(int k = 0; k < FEAT; k++) s += smem[k]*Wf1[k*H + f];
    float c = fmaxf(s, 0.f) * Wf2[f];

    float x1p = (f < F) ? pooled[(size_t)g*F + f]*Wg[f] : 0.f;
    for(int off = 32; off; off >>= 1){
        c   += __shfl_down(c,   off, 64);
        x1p += __shfl_down(x1p, off, 64);
    }
    float* red = smem + FEAT;
    if((threadIdx.x & 63) == 0){
        red[threadIdx.x >> 6]       = c;
        red[2 + (threadIdx.x >> 6)] = x1p;
    }
    __syncthreads();
    if(threadIdx.x == 0){
        float x2 = red[0] + red[1] + bf2[0];
        float x1 = fmaxf(red[2] + red[3] + bg[0], 0.f);
        out[g] = x1 + x2;
    }
}

extern "C" void kernel_launch(void* const* d_in, const int* in_sizes, int n_in,
                              void* d_out, int out_size, void* d_ws, size_t ws_size,
                              hipStream_t stream) {
    const float* x       = (const float*)d_in[0];
    const int*   ei      = (const int*)  d_in[1];
    const int*   batch   = (const int*)  d_in[2];
    const float* feature = (const float*)d_in[3];
    const float* W1 = (const float*)d_in[4];  const float* b1 = (const float*)d_in[5];
    const float* W2 = (const float*)d_in[6];  const float* b2 = (const float*)d_in[7];
    const float* W3 = (const float*)d_in[8];  const float* b3 = (const float*)d_in[9];
    const float* Wg = (const float*)d_in[10]; const float* bg = (const float*)d_in[11];
    const float* Wf1= (const float*)d_in[12]; const float* bf1= (const float*)d_in[13];
    const float* Wf2= (const float*)d_in[14]; const float* bf2= (const float*)d_in[15];
    float* out = (float*)d_out;

    const int N    = in_sizes[2];          // 100000
    const int E    = in_sizes[1] / 2;      // 1000000
    const int G    = out_size;             // 1024
    const int F    = in_sizes[5];          // 44
    const int F2   = in_sizes[7];          // 88
    const int FEAT = in_sizes[3] / G;      // 1019
    const int H    = in_sizes[13];         // 128
    const int F4   = F  / 4;               // 11
    const int F24  = F2 / 4;               // 22

    const int NB    = cdiv(N, 1 << BSH);   // 98 coarse buckets
    const int chunk = cdiv(E, NBLK1);      // edges per pass-1 block
    const int M     = NB * NBLK1;          // count-matrix size

    // workspace layout (4B units)
    float* wsf    = (float*)d_ws;
    float* dinv   = wsf;                        // N floats
    int*   cursor = (int*)(dinv + N);           // N ints
    int*   csr    = cursor + N;                 // E ints
    float* bufA   = (float*)(csr + E);          // N*F
    float* bufB   = bufA + (size_t)N*F;         // N*F2
    float* bufC   = bufB + (size_t)N*F2;        // N*F
    float* pooled = bufC + (size_t)N*F;         // G*F
    // pairs + cnt_t time-share bufB (dead until conv2's GEMM writes bufB)
    int2*  pairs  = (int2*)bufB;                // E int2
    int*   cnt_t  = (int*)bufB + 2*(size_t)E;   // M ints

    // ---- CSR build (counting sort; no global atomics) ----
    k_bcount  <<<NBLK1, TPB, 0, stream>>>(ei + E, cnt_t, E, NB, chunk);
    k_bscan   <<<1, 1024, 0, stream>>>(cnt_t, M);
    k_bscatter<<<NBLK1, TPB, 0, stream>>>(ei, cnt_t, pairs, E, NB, chunk);
    k_build   <<<NB, TPB, 0, stream>>>(pairs, cnt_t, csr, cursor, dinv, N, E, NB);

    // ---- conv1 (transform-first): t' = dinv.*(x@W1) ; h1' = dinv.*relu(dinv*agg + b1) ----
    {
        unsigned tot = (unsigned)N*F4;
        k_gemm<<<cdiv(tot,TPB), TPB, F*F*sizeof(float), stream>>>(x, W1, bufA, N, F, F4, dinv, nullptr);
        k_gather<<<cdiv(tot,TPB), TPB, 0, stream>>>(cursor, csr, bufA, dinv, b1, bufC, N, F4, 1);
    }
    // ---- conv2 (aggregate-first): a = dinv*agg(h1') ; h2 = relu(a@W2 + b2) ----
    {
        unsigned tot = (unsigned)N*F4;
        k_gather<<<cdiv(tot,TPB), TPB, 0, stream>>>(cursor, csr, bufC, dinv, nullptr, bufA, N, F4, 0);
        unsigned tot2 = (unsigned)N*F24;
        k_gemm<<<cdiv(tot2,TPB), TPB, F*F2*sizeof(float), stream>>>(bufA, W2, bufB, N, F, F24, nullptr, b2);
    }
    // ---- conv3 (transform-first): t' = dinv.*(h2@W3) ; h3 = relu(dinv*agg + b3) ----
    {
        unsigned tot = (unsigned)N*F4;
        k_gemm<<<cdiv(tot,TPB), TPB, F2*F*sizeof(float), stream>>>(bufB, W3, bufA, N, F2, F4, dinv, nullptr);
        k_gather<<<cdiv(tot,TPB), TPB, 0, stream>>>(cursor, csr, bufA, dinv, b3, bufC, N, F4, 0);
    }
    // ---- global max pool ----
    k_pool_seg<<<G, 64, 0, stream>>>(bufC, batch, pooled, N, F4);

    // ---- heads ----
    k_head<<<G, H, (FEAT + 4)*sizeof(float), stream>>>(
        feature, Wf1, bf1, Wf2, bf2, pooled, Wg, bg, out, FEAT, H, F);
}